// Round 1
// baseline (929.391 us; speedup 1.0000x reference)
//
#include <hip/hip_runtime.h>
#include <math.h>

// Problem constants (from setup_inputs): B=16, K=6, H=W=640
#define BB   16
#define KCH  6
#define CH   7          // K+1 channels in pred
#define NN   409600     // H*W
#define N4   102400     // NN/4 (float4 count)
#define EPSF 1e-6f

// Workspace layout in 32-bit words:
//   hist[4 passes][BB][256]  : 16384 words
//   pos[BB], negtot[BB], prefix[BB], rank[BB], thrbits[BB], useohem[BB]
//   textsums[BB][3]  (float)
//   kernsums[KCH][BB][3] (float)
#define HIST_OFF 0
#define POS_OFF  16384
#define NEGT_OFF 16400
#define PRE_OFF  16416
#define RANK_OFF 16432
#define THR_OFF  16448
#define UOH_OFF  16464
#define TEXT_OFF 16480
#define KERN_OFF 16528
#define WS_WORDS 16816   // ~66 KB

__device__ __forceinline__ unsigned sortkey(float f) {
    // monotone float->uint map (ascending float == ascending uint)
    unsigned u = __float_as_uint(f);
    return (u & 0x80000000u) ? ~u : (u | 0x80000000u);
}
__device__ __forceinline__ float sigmoidf_(float x) { return 1.0f / (1.0f + expf(-x)); }

__device__ __forceinline__ float wred(float v) {
#pragma unroll
    for (int o = 32; o > 0; o >>= 1) v += __shfl_down(v, o, 64);
    return v;
}
__device__ __forceinline__ unsigned wredu(unsigned v) {
#pragma unroll
    for (int o = 32; o > 0; o >>= 1) v += __shfl_down(v, o, 64);
    return v;
}

// Pass A: per-batch pos/neg counts + pass-0 (top byte) histogram of sort keys.
__global__ __launch_bounds__(256) void k_count_hist0(const float* __restrict__ pred,
                                                     const float* __restrict__ gt,
                                                     const float* __restrict__ tm,
                                                     unsigned* __restrict__ ws) {
    const int b = blockIdx.y;
    const int t = threadIdx.x;
    __shared__ unsigned h[256][16];   // [bin][copy] -> copies spread across banks
    for (int i = t; i < 256 * 16; i += 256) ((unsigned*)h)[i] = 0;
    __syncthreads();

    const float4* p4 = (const float4*)(pred + (size_t)b * CH * NN + (size_t)KCH * NN);
    const float4* g4 = (const float4*)(gt + (size_t)b * NN);
    const float4* m4 = (const float4*)(tm + (size_t)b * NN);
    const int copy = t & 15;

    unsigned lpos = 0, lneg = 0;
    for (int i = blockIdx.x * 256 + t; i < N4; i += gridDim.x * 256) {
        float4 p = p4[i], g = g4[i], m = m4[i];
#pragma unroll
        for (int j = 0; j < 4; j++) {
            float pf = (&p.x)[j], gf = (&g.x)[j], mf = (&m.x)[j];
            bool neg = (gf <= 0.5f);
            lneg += neg ? 1u : 0u;
            lpos += (gf > 0.5f && mf > 0.5f) ? 1u : 0u;
            unsigned key = neg ? sortkey(pf) : 0u;
            atomicAdd(&h[key >> 24][copy], 1u);
        }
    }
    lpos = wredu(lpos); lneg = wredu(lneg);
    if ((t & 63) == 0) {
        atomicAdd(&ws[POS_OFF + b], lpos);
        atomicAdd(&ws[NEGT_OFF + b], lneg);
    }
    __syncthreads();
    // reduce the 16 copies, emit to global histogram
    if (t < 256) {
        unsigned s = 0;
#pragma unroll
        for (int c = 0; c < 16; c++) s += h[t][c];
        if (s) atomicAdd(&ws[HIST_OFF + (0 * BB + b) * 256 + t], s);
    }
}

// Histogram for radix pass 1..3 (recompute keys; pred_texts+gt are L3-hot).
__global__ __launch_bounds__(256) void k_hist(const float* __restrict__ pred,
                                              const float* __restrict__ gt,
                                              unsigned* __restrict__ ws, int pass) {
    const int b = blockIdx.y;
    const int t = threadIdx.x;
    const unsigned prefix = ws[PRE_OFF + b];
    const int shift = 24 - 8 * pass;
    __shared__ unsigned h[256][16];
    for (int i = t; i < 256 * 16; i += 256) ((unsigned*)h)[i] = 0;
    __syncthreads();

    const float4* p4 = (const float4*)(pred + (size_t)b * CH * NN + (size_t)KCH * NN);
    const float4* g4 = (const float4*)(gt + (size_t)b * NN);
    const int copy = t & 15;

    for (int i = blockIdx.x * 256 + t; i < N4; i += gridDim.x * 256) {
        float4 p = p4[i], g = g4[i];
#pragma unroll
        for (int j = 0; j < 4; j++) {
            float pf = (&p.x)[j], gf = (&g.x)[j];
            unsigned key = (gf <= 0.5f) ? sortkey(pf) : 0u;
            if ((key >> (shift + 8)) == prefix)
                atomicAdd(&h[(key >> shift) & 0xFFu][copy], 1u);
        }
    }
    __syncthreads();
    if (t < 256) {
        unsigned s = 0;
#pragma unroll
        for (int c = 0; c < 16; c++) s += h[t][c];
        if (s) atomicAdd(&ws[HIST_OFF + (pass * BB + b) * 256 + t], s);
    }
}

// Scan one radix level per batch: pick the bin containing rank r (from the top).
__global__ void k_scan(unsigned* __restrict__ ws, int pass) {
    const int b = blockIdx.x;
    if (threadIdx.x != 0) return;
    const unsigned* h = ws + HIST_OFF + (pass * BB + b) * 256;
    unsigned r, prefix;
    if (pass == 0) {
        unsigned pos = ws[POS_OFF + b];
        unsigned ntot = ws[NEGT_OFF + b];
        unsigned negnum = min(3u * pos, ntot);
        ws[UOH_OFF + b] = (pos > 0u && negnum > 0u) ? 1u : 0u;
        r = (negnum > 0u) ? negnum : 1u;   // idx = clip(neg_num-1,0,N-1) -> rank max(neg_num,1)
        prefix = 0u;
    } else {
        r = ws[RANK_OFF + b];
        prefix = ws[PRE_OFF + b];
    }
    unsigned cum = 0; unsigned sel = 0;
    for (int bin = 255; bin >= 0; bin--) {
        unsigned c = h[bin];
        if (cum + c >= r) { sel = (unsigned)bin; r = r - cum; break; }
        cum += c;
    }
    prefix = (prefix << 8) | sel;
    ws[PRE_OFF + b] = prefix;
    ws[RANK_OFF + b] = r;
    if (pass == 3) {
        // invert monotone map: key -> original float bits
        unsigned key = prefix;
        unsigned orig = (key & 0x80000000u) ? (key & 0x7FFFFFFFu) : ~key;
        ws[THR_OFF + b] = orig;
    }
}

// Text dice partial sums with OHEM-selected mask.
__global__ __launch_bounds__(256) void k_textdice(const float* __restrict__ pred,
                                                  const float* __restrict__ gt,
                                                  const float* __restrict__ tm,
                                                  unsigned* __restrict__ ws) {
    const int b = blockIdx.y;
    const float thr = __uint_as_float(ws[THR_OFF + b]);
    const bool useoh = (ws[UOH_OFF + b] != 0u);
    const float4* p4 = (const float4*)(pred + (size_t)b * CH * NN + (size_t)KCH * NN);
    const float4* g4 = (const float4*)(gt + (size_t)b * NN);
    const float4* m4 = (const float4*)(tm + (size_t)b * NN);

    float la = 0.f, lb = 0.f, lc = 0.f;
    for (int i = blockIdx.x * 256 + threadIdx.x; i < N4; i += gridDim.x * 256) {
        float4 p = p4[i], g = g4[i], m = m4[i];
#pragma unroll
        for (int j = 0; j < 4; j++) {
            float pf = (&p.x)[j], gf = (&g.x)[j], mf = (&m.x)[j];
            float sel;
            if (useoh)
                sel = (((pf >= thr) || (gf > 0.5f)) && (mf > 0.5f)) ? 1.f : 0.f;
            else
                sel = mf;
            float pp = sigmoidf_(pf) * sel;
            float gg = gf * sel;
            la += pp * gg; lb += pp * pp; lc += gg * gg;
        }
    }
    la = wred(la); lb = wred(lb); lc = wred(lc);
    float* ts = (float*)(ws + TEXT_OFF);
    if ((threadIdx.x & 63) == 0) {
        atomicAdd(&ts[b * 3 + 0], la);
        atomicAdd(&ts[b * 3 + 1], lb);
        atomicAdd(&ts[b * 3 + 2], lc);
    }
}

// Kernel-branch dice sums (independent of OHEM): one streaming pass.
__global__ __launch_bounds__(256) void k_kerndice(const float* __restrict__ pred,
                                                  const float* __restrict__ gtk,
                                                  const float* __restrict__ tm,
                                                  unsigned* __restrict__ ws) {
    const int b = blockIdx.y;
    const float4* pt4 = (const float4*)(pred + (size_t)b * CH * NN + (size_t)KCH * NN);
    const float4* m4  = (const float4*)(tm + (size_t)b * NN);

    float acc[KCH][3];
#pragma unroll
    for (int k = 0; k < KCH; k++) { acc[k][0] = acc[k][1] = acc[k][2] = 0.f; }

    for (int i = blockIdx.x * 256 + threadIdx.x; i < N4; i += gridDim.x * 256) {
        float4 pt = pt4[i], m = m4[i];
        float km[4];
        km[0] = (pt.x > 0.f && m.x > 0.5f) ? 1.f : 0.f;
        km[1] = (pt.y > 0.f && m.y > 0.5f) ? 1.f : 0.f;
        km[2] = (pt.z > 0.f && m.z > 0.5f) ? 1.f : 0.f;
        km[3] = (pt.w > 0.f && m.w > 0.5f) ? 1.f : 0.f;
#pragma unroll
        for (int k = 0; k < KCH; k++) {
            float4 pk = ((const float4*)(pred + (size_t)b * CH * NN + (size_t)k * NN))[i];
            float4 gk = ((const float4*)(gtk + (size_t)b * KCH * NN + (size_t)k * NN))[i];
#pragma unroll
            for (int j = 0; j < 4; j++) {
                float pf = (&pk.x)[j], gf = (&gk.x)[j], mm = km[j];
                float pp = sigmoidf_(pf) * mm;
                float gg = gf * mm;
                acc[k][0] += pp * gg; acc[k][1] += pp * pp; acc[k][2] += gg * gg;
            }
        }
    }
    float* kf = (float*)(ws + KERN_OFF);
#pragma unroll
    for (int k = 0; k < KCH; k++) {
#pragma unroll
        for (int j = 0; j < 3; j++) {
            float v = wred(acc[k][j]);
            if ((threadIdx.x & 63) == 0) atomicAdd(&kf[(k * BB + b) * 3 + j], v);
        }
    }
}

__global__ void k_final(const unsigned* __restrict__ ws, float* __restrict__ out) {
    if (threadIdx.x != 0 || blockIdx.x != 0) return;
    const float* ts = (const float*)(ws + TEXT_OFF);
    const float* ks = (const float*)(ws + KERN_OFF);
    float lt = 0.f;
    for (int b = 0; b < BB; b++) {
        float a = ts[b * 3 + 0], p2 = ts[b * 3 + 1], g2 = ts[b * 3 + 2];
        lt += 1.0f - 2.0f * a / (p2 + g2 + 2.0f * EPSF);
    }
    lt *= (1.0f / BB);
    float lk = 0.f;
    for (int i = 0; i < KCH * BB; i++) {
        float a = ks[i * 3 + 0], p2 = ks[i * 3 + 1], g2 = ks[i * 3 + 2];
        lk += 1.0f - 2.0f * a / (p2 + g2 + 2.0f * EPSF);
    }
    lk *= (1.0f / (KCH * BB));
    out[0] = 0.7f * lt + 0.3f * lk;
}

extern "C" void kernel_launch(void* const* d_in, const int* in_sizes, int n_in,
                              void* d_out, int out_size, void* d_ws, size_t ws_size,
                              hipStream_t stream) {
    const float* pred = (const float*)d_in[0];   // (16,7,640,640)
    const float* gt   = (const float*)d_in[1];   // (16,640,640)
    const float* gtk  = (const float*)d_in[2];   // (16,6,640,640)
    const float* tm   = (const float*)d_in[3];   // (16,640,640)
    float* out = (float*)d_out;
    unsigned* ws = (unsigned*)d_ws;

    hipMemsetAsync(ws, 0, (size_t)WS_WORDS * 4, stream);

    dim3 blk(256);
    dim3 gridA(128, BB);

    // counts + pass-0 histogram (also kicks off independent kernel-dice pass)
    k_count_hist0<<<gridA, blk, 0, stream>>>(pred, gt, tm, ws);
    k_kerndice<<<dim3(100, BB), blk, 0, stream>>>(pred, gtk, tm, ws);

    k_scan<<<BB, 64, 0, stream>>>(ws, 0);
    k_hist<<<gridA, blk, 0, stream>>>(pred, gt, ws, 1);
    k_scan<<<BB, 64, 0, stream>>>(ws, 1);
    k_hist<<<gridA, blk, 0, stream>>>(pred, gt, ws, 2);
    k_scan<<<BB, 64, 0, stream>>>(ws, 2);
    k_hist<<<gridA, blk, 0, stream>>>(pred, gt, ws, 3);
    k_scan<<<BB, 64, 0, stream>>>(ws, 3);

    k_textdice<<<gridA, blk, 0, stream>>>(pred, gt, tm, ws);
    k_final<<<1, 64, 0, stream>>>(ws, out);
}